// Round 23
// baseline (119.707 us; speedup 1.0000x reference)
//
#include <hip/hip_runtime.h>
#include <hip/hip_bf16.h>
#include <math.h>

// ROUND 23 = ROUND 18 (best, 85.3us) + precompute launched 3x total
// (2 extra copies write to dummy buffers). Measurement round:
// warm precompute cost per launch = (dur_us - 85.3) / 2.

#define NATOMS 1280
#define NHEAD 4
#define DHEAD 16
#define EEDGE 5120
#define MKV 12800
#define NLAYERS 4
#define NGRAPH 32
#define NPG 40      // atoms per graph
#define MPG 400     // kv per graph
#define QH 10       // q rows per attention block (quarter graph)

__device__ __forceinline__ unsigned short f2bf(float x) {
  __hip_bfloat16 h = __float2bfloat16(x);
  return *reinterpret_cast<unsigned short*>(&h);
}
__device__ __forceinline__ float bflo(unsigned int u) {
  union { unsigned int i; float f; } c; c.i = u << 16; return c.f;
}
__device__ __forceinline__ float bfhi(unsigned int u) {
  union { unsigned int i; float f; } c; c.i = u & 0xffff0000u; return c.f;
}

// ---- precompute: EW GEMM + KV GEMM (bf16) + agg zero + Wmq = Wm@Wq ----------
// blocks [0,320): EW; [320,1120): KV; [1120,1200): zero agg; [1200,1204): Wmq
__global__ __launch_bounds__(256) void precompute_kernel(
    const float* __restrict__ edge_attr, const float* __restrict__ Kin,
    const float* __restrict__ Vin, const float* __restrict__ We,
    const float* __restrict__ Wk, const float* __restrict__ Wv,
    const float* __restrict__ Wm, const float* __restrict__ Wq,
    float* __restrict__ EW, unsigned short* __restrict__ Khb,
    unsigned short* __restrict__ Vhb, float* __restrict__ agg,
    float* __restrict__ Wmq) {
  __shared__ float aT[64][132];  // A tile transposed [k][row], padded
  __shared__ float wS[64][64];
  const int b = blockIdx.x, t = threadIdx.x;

  if (b < 320) {  // ---- EW[l] = edge_attr @ We[l], 64-row tiles, K=16 ----
    int l = b / 80, et = b % 80;
    const float* A = edge_attr + (size_t)et * 64 * 16;
    const float* W = We + l * 1024;
    float* C = EW + ((size_t)l * EEDGE + et * 64) * 64;
    {
      int r = t >> 2, c0 = (t & 3) * 4;
      float4 v = *(const float4*)(A + r * 16 + c0);
      aT[c0 + 0][r] = v.x; aT[c0 + 1][r] = v.y;
      aT[c0 + 2][r] = v.z; aT[c0 + 3][r] = v.w;
      float4 w = ((const float4*)W)[t];
      *(float4*)&wS[t >> 4][(t & 15) * 4] = w;
    }
    __syncthreads();
    const int rb = (t >> 4) * 4, cb = (t & 15) * 4;
    float acc[4][4] = {};
#pragma unroll
    for (int k = 0; k < 16; ++k) {
      float4 a = *(const float4*)&aT[k][rb];
      float4 w = *(const float4*)&wS[k][cb];
      acc[0][0] += a.x * w.x; acc[0][1] += a.x * w.y; acc[0][2] += a.x * w.z; acc[0][3] += a.x * w.w;
      acc[1][0] += a.y * w.x; acc[1][1] += a.y * w.y; acc[1][2] += a.y * w.z; acc[1][3] += a.y * w.w;
      acc[2][0] += a.z * w.x; acc[2][1] += a.z * w.y; acc[2][2] += a.z * w.z; acc[2][3] += a.z * w.w;
      acc[3][0] += a.w * w.x; acc[3][1] += a.w * w.y; acc[3][2] += a.w * w.z; acc[3][3] += a.w * w.w;
    }
#pragma unroll
    for (int i = 0; i < 4; ++i)
      *(float4*)(C + (size_t)(rb + i) * 64 + cb) =
          make_float4(acc[i][0], acc[i][1], acc[i][2], acc[i][3]);
  } else if (b < 1120) {  // ---- Kh/Vh = {K,V} @ {Wk,Wv}[l] -> bf16 ----
    int tid = b - 320;
    int gy = tid / 100, rt = tid % 100;
    int which = gy >> 2, l = gy & 3;
    const float* A = (which ? Vin : Kin) + (size_t)rt * 128 * 64;
    const float* W = (which ? Wv : Wk) + l * 4096;
    unsigned short* C =
        (which ? Vhb : Khb) + ((size_t)l * MKV + rt * 128) * 64;
    for (int i = t; i < 2048; i += 256) {  // 128 rows x 16 float4, transpose
      int r = i >> 4, c0 = (i & 15) * 4;
      float4 v = *(const float4*)(A + r * 64 + c0);
      aT[c0 + 0][r] = v.x; aT[c0 + 1][r] = v.y;
      aT[c0 + 2][r] = v.z; aT[c0 + 3][r] = v.w;
    }
    for (int i = t; i < 1024; i += 256) {
      float4 v = ((const float4*)W)[i];
      *(float4*)&wS[i >> 4][(i & 15) * 4] = v;
    }
    __syncthreads();
    const int rb = (t >> 4) * 8, cb = (t & 15) * 4;
    float acc[8][4] = {};
#pragma unroll 4
    for (int k = 0; k < 64; ++k) {
      float4 a0 = *(const float4*)&aT[k][rb];
      float4 a1 = *(const float4*)&aT[k][rb + 4];
      float4 w = *(const float4*)&wS[k][cb];
      acc[0][0] += a0.x * w.x; acc[0][1] += a0.x * w.y; acc[0][2] += a0.x * w.z; acc[0][3] += a0.x * w.w;
      acc[1][0] += a0.y * w.x; acc[1][1] += a0.y * w.y; acc[1][2] += a0.y * w.z; acc[1][3] += a0.y * w.w;
      acc[2][0] += a0.z * w.x; acc[2][1] += a0.z * w.y; acc[2][2] += a0.z * w.z; acc[2][3] += a0.z * w.w;
      acc[3][0] += a0.w * w.x; acc[3][1] += a0.w * w.y; acc[3][2] += a0.w * w.z; acc[3][3] += a0.w * w.w;
      acc[4][0] += a1.x * w.x; acc[4][1] += a1.x * w.y; acc[4][2] += a1.x * w.z; acc[4][3] += a1.x * w.w;
      acc[5][0] += a1.y * w.x; acc[5][1] += a1.y * w.y; acc[5][2] += a1.y * w.z; acc[5][3] += a1.y * w.w;
      acc[6][0] += a1.z * w.x; acc[6][1] += a1.z * w.y; acc[6][2] += a1.z * w.z; acc[6][3] += a1.z * w.w;
      acc[7][0] += a1.w * w.x; acc[7][1] += a1.w * w.y; acc[7][2] += a1.w * w.z; acc[7][3] += a1.w * w.w;
    }
#pragma unroll
    for (int i = 0; i < 8; ++i) {
      ushort4 o;
      o.x = f2bf(acc[i][0]); o.y = f2bf(acc[i][1]);
      o.z = f2bf(acc[i][2]); o.w = f2bf(acc[i][3]);
      *(ushort4*)(C + (size_t)(rb + i) * 64 + cb) = o;
    }
  } else if (b < 1200) {  // ---- zero agg (all layers) ----
    int i = (b - 1120) * 256 + t;
    float4 z = make_float4(0.f, 0.f, 0.f, 0.f);
    for (int j = i; j < NLAYERS * NATOMS * 16; j += 80 * 256)
      ((float4*)agg)[j] = z;
  } else {  // ---- Wmq[l] = Wm[l] @ Wq[l], one block per layer ----
    int l = b - 1200;
    const float* A = Wm + l * 4096;
    const float* B = Wq + l * 4096;
    for (int i = t; i < 1024; i += 256) {
      float4 v = ((const float4*)A)[i];
      *(float4*)&aT[i >> 4][(i & 15) * 4] = v;   // aT holds Wm row-major
    }
    for (int i = t; i < 1024; i += 256) {
      float4 v = ((const float4*)B)[i];
      *(float4*)&wS[i >> 4][(i & 15) * 4] = v;
    }
    __syncthreads();
    int r = t >> 2, c0 = (t & 3) * 16;
    float acc[16] = {};
    for (int j = 0; j < 64; ++j) {
      float a = aT[r][j];
#pragma unroll
      for (int c = 0; c < 16; ++c) acc[c] += a * wS[j][c0 + c];
    }
#pragma unroll
    for (int c = 0; c < 16; c += 4)
      *(float4*)(Wmq + (size_t)l * 4096 + r * 64 + c0 + c) =
          make_float4(acc[c], acc[c + 1], acc[c + 2], acc[c + 3]);
  }
}

// -- per layer: edge messages + scatter-add, AND init xout = xin (residual) ---
__global__ void edge_copy_kernel(const float* __restrict__ xin,
                                 const float* __restrict__ EWl,
                                 const int* __restrict__ src,
                                 const int* __restrict__ dst,
                                 float* __restrict__ agg,
                                 float* __restrict__ xout) {
  int idx = blockIdx.x * 256 + threadIdx.x;  // covers E*64 = 327680
  if (idx < NATOMS * 64) xout[idx] = xin[idx];
  int e = idx >> 6, f = idx & 63;
  float m = xin[src[e] * 64 + f] + EWl[idx];
  m = m / (1.f + __expf(-m));  // silu
  atomicAdd(&agg[dst[e] * 64 + f], m);
}

// -- fused attention (r18 version, unchanged) ---------------------------------
__global__ __launch_bounds__(512) void fused_attn_kernel(
    const float* __restrict__ xin, const float* __restrict__ agg,
    const float* __restrict__ Wq, const float* __restrict__ Wmq,
    const float* __restrict__ Wo, const unsigned short* __restrict__ Khb,
    const unsigned short* __restrict__ Vhb, float* __restrict__ xout) {
  __shared__ union {
    unsigned int Ks2[MPG][9];
    struct {
      float part[16][QH][16];
      float psum[16][QH];
    } r;
  } ku;
  __shared__ unsigned int Vs2[MPG][10];
  __shared__ float P[QH][401];
  __shared__ float Qs[QH][16];

  const int g = blockIdx.x, hd = blockIdx.y, qq = blockIdx.z;
  const int t = threadIdx.x;
  const int hoff = hd * DHEAD;
  const int qbase = g * NPG + qq * QH;
  const int kbase = g * MPG;
  const unsigned int* Kh2 = (const unsigned int*)Khb;
  const unsigned int* Vh2 = (const unsigned int*)Vhb;
  const int hw = hoff >> 1;

  // phase 0: stage K,V (bf16 pairs) + Q head-slice = 0.25*(x@Wq + agg@Wmq)
  for (int i = t; i < MPG * 8; i += 512) {
    int k = i >> 3, j = i & 7;
    ku.Ks2[k][j] = Kh2[(size_t)(kbase + k) * 32 + hw + j];
    Vs2[k][j] = Vh2[(size_t)(kbase + k) * 32 + hw + j];
  }
  if (t < QH * 16) {
    int q = t >> 4, d = t & 15;
    const float* xrow = xin + (qbase + q) * 64;
    const float* arow = agg + (qbase + q) * 64;
    float acc = 0.f;
#pragma unroll 16
    for (int k = 0; k < 64; ++k)
      acc += xrow[k] * Wq[k * 64 + hoff + d] + arow[k] * Wmq[k * 64 + hoff + d];
    Qs[q][d] = acc * 0.25f;
  }
  __syncthreads();

  // phase 1: scores + fused exp (no max; |s| small, f32-safe).
  if (t < 400) {
    const int qg = (t < 200) ? 0 : 5;
    const int kg = (t < 200) ? t : t - 200;
    float acc[5][2] = {};
#pragma unroll
    for (int j = 0; j < 8; ++j) {
      unsigned int ka = ku.Ks2[kg][j], kb = ku.Ks2[kg + 200][j];
      float ka0 = bflo(ka), ka1 = bfhi(ka);
      float kb0 = bflo(kb), kb1 = bfhi(kb);
#pragma unroll
      for (int i = 0; i < 5; ++i) {
        float q0 = Qs[qg + i][2 * j], q1 = Qs[qg + i][2 * j + 1];
        acc[i][0] += q0 * ka0 + q1 * ka1;
        acc[i][1] += q0 * kb0 + q1 * kb1;
      }
    }
#pragma unroll
    for (int i = 0; i < 5; ++i) {
      P[qg + i][kg] = __expf(acc[i][0]);
      P[qg + i][kg + 200] = __expf(acc[i][1]);
    }
  }
  __syncthreads();

  // phase 2: PV register-tiled, 16-way k-split (320 threads): 2q x 4d x 25k.
  if (t < 320) {
    const int dg = (t & 3) * 4;
    const int qp = ((t >> 2) % 5) * 2;
    const int ks = t / 20;
    const int k0 = ks * 25;
    float a0[4] = {}, a1[4] = {};
    float s0 = 0.f, s1 = 0.f;
    for (int k = k0; k < k0 + 25; ++k) {
      float p0 = P[qp][k], p1 = P[qp + 1][k];
      uint2 vv = *(const uint2*)&Vs2[k][dg >> 1];
      float v0 = bflo(vv.x), v1 = bfhi(vv.x);
      float v2 = bflo(vv.y), v3 = bfhi(vv.y);
      a0[0] += p0 * v0; a0[1] += p0 * v1; a0[2] += p0 * v2; a0[3] += p0 * v3;
      a1[0] += p1 * v0; a1[1] += p1 * v1; a1[2] += p1 * v2; a1[3] += p1 * v3;
      s0 += p0; s1 += p1;
    }
    *(float4*)&ku.r.part[ks][qp][dg] = make_float4(a0[0], a0[1], a0[2], a0[3]);
    *(float4*)&ku.r.part[ks][qp + 1][dg] = make_float4(a1[0], a1[1], a1[2], a1[3]);
    if (dg == 0) {
      ku.r.psum[ks][qp] = s0;
      ku.r.psum[ks][qp + 1] = s1;
    }
  }
  __syncthreads();

  // phase 3: reduce partials + sums, normalize -> reuse Qs as o_head
  if (t < QH * 16) {
    int q = t >> 4, d = t & 15;
    float o = 0.f, s = 0.f;
#pragma unroll
    for (int ks = 0; ks < 16; ++ks) {
      o += ku.r.part[ks][q][d];
      s += ku.r.psum[ks][q];
    }
    Qs[q][d] = o / s;
  }
  __syncthreads();

  // phase 4: out-projection partial for this head -> atomicAdd into xout
  for (int i = t; i < QH * 64; i += 512) {
    int q = i >> 6, f = i & 63;
    float acc = 0.f;
#pragma unroll
    for (int d = 0; d < DHEAD; ++d) acc += Qs[q][d] * Wo[(hoff + d) * 64 + f];
    atomicAdd(&xout[(qbase + q) * 64 + f], acc);
  }
}

extern "C" void kernel_launch(void* const* d_in, const int* in_sizes, int n_in,
                              void* d_out, int out_size, void* d_ws, size_t ws_size,
                              hipStream_t stream) {
  const float* x        = (const float*)d_in[0];
  const float* edge_attr= (const float*)d_in[1];
  const float* K        = (const float*)d_in[2];
  const float* V        = (const float*)d_in[3];
  const float* We       = (const float*)d_in[4];
  const float* Wm       = (const float*)d_in[5];
  const float* Wq       = (const float*)d_in[6];
  const float* Wk       = (const float*)d_in[7];
  const float* Wv       = (const float*)d_in[8];
  const float* Wo       = (const float*)d_in[9];
  const int*   eidx     = (const int*)d_in[10];
  const int*   src      = eidx;
  const int*   dst      = eidx + EEDGE;

  unsigned short* Khb = (unsigned short*)d_ws;          // 4*12800*64 bf16
  unsigned short* Vhb = Khb + (size_t)NLAYERS * MKV * 64;
  float* EW   = (float*)(Vhb + (size_t)NLAYERS * MKV * 64);  // 4*5120*64 f32
  float* agg  = EW + (size_t)NLAYERS * EEDGE * 64;           // 4*1280*64
  float* xA   = agg + (size_t)NLAYERS * NATOMS * 64;
  float* xB   = xA + NATOMS * 64;
  float* Wmq  = xB + NATOMS * 64;                            // 4*64*64
  // ---- dummy region for measurement duplicates ----
  unsigned short* KhbD = (unsigned short*)(Wmq + NLAYERS * 4096);
  unsigned short* VhbD = KhbD + (size_t)NLAYERS * MKV * 64;
  float* EWD  = (float*)(VhbD + (size_t)NLAYERS * MKV * 64);
  float* aggD = EWD + (size_t)NLAYERS * EEDGE * 64;
  float* WmqD = aggD + (size_t)NLAYERS * NATOMS * 64;

  // real precompute + 2 measurement duplicates (warm caches, dummy sinks)
  precompute_kernel<<<1204, 256, 0, stream>>>(edge_attr, K, V, We, Wk, Wv,
                                              Wm, Wq, EW, Khb, Vhb, agg, Wmq);
  precompute_kernel<<<1204, 256, 0, stream>>>(edge_attr, K, V, We, Wk, Wv,
                                              Wm, Wq, EWD, KhbD, VhbD, aggD, WmqD);
  precompute_kernel<<<1204, 256, 0, stream>>>(edge_attr, K, V, We, Wk, Wv,
                                              Wm, Wq, EWD, KhbD, VhbD, aggD, WmqD);

  const float* xin = x;
  for (int l = 0; l < NLAYERS; ++l) {
    float* aggl = agg + (size_t)l * NATOMS * 64;
    float* xout = (l == NLAYERS - 1) ? (float*)d_out : ((l & 1) ? xB : xA);
    edge_copy_kernel<<<EEDGE * 64 / 256, 256, 0, stream>>>(
        xin, EW + (size_t)l * EEDGE * 64, src, dst, aggl, xout);
    fused_attn_kernel<<<dim3(NGRAPH, NHEAD, 4), 512, 0, stream>>>(
        xin, aggl, Wq + l * 4096, Wmq + (size_t)l * 4096, Wo + l * 4096,
        Khb + (size_t)l * MKV * 64, Vhb + (size_t)l * MKV * 64, xout);
    xin = xout;
  }
}

// Round 24
// 80.546 us; speedup vs baseline: 1.4862x; 1.4862x over previous
//
#include <hip/hip_runtime.h>
#include <hip/hip_bf16.h>
#include <math.h>

#define NATOMS 1280
#define NHEAD 4
#define DHEAD 16
#define EEDGE 5120
#define MKV 12800
#define NLAYERS 4
#define NGRAPH 32
#define NPG 40      // atoms per graph
#define MPG 400     // kv per graph
#define QH 10       // q rows per attention block (quarter graph)

typedef __attribute__((ext_vector_type(8))) short bf16x8;
typedef __attribute__((ext_vector_type(4))) float f32x4;

__device__ __forceinline__ unsigned short f2bf(float x) {
  __hip_bfloat16 h = __float2bfloat16(x);
  return *reinterpret_cast<unsigned short*>(&h);
}
__device__ __forceinline__ float bflo(unsigned int u) {
  union { unsigned int i; float f; } c; c.i = u << 16; return c.f;
}
__device__ __forceinline__ float bfhi(unsigned int u) {
  union { unsigned int i; float f; } c; c.i = u & 0xffff0000u; return c.f;
}

// ---- precompute: EW GEMM + KV MFMA-GEMM (bf16) + agg zero + Wmq = Wm@Wq -----
// blocks [0,320): EW; [320,1920): KV via MFMA; [1920,2000): zero agg;
// [2000,2004): Wmq
__global__ __launch_bounds__(256) void precompute_kernel(
    const float* __restrict__ edge_attr, const float* __restrict__ Kin,
    const float* __restrict__ Vin, const float* __restrict__ We,
    const float* __restrict__ Wk, const float* __restrict__ Wv,
    const float* __restrict__ Wm, const float* __restrict__ Wq,
    float* __restrict__ EW, unsigned short* __restrict__ Khb,
    unsigned short* __restrict__ Vhb, float* __restrict__ agg,
    float* __restrict__ Wmq) {
  __shared__ float aT[64][132];  // A tile transposed (EW/Wmq branches)
  __shared__ float wS[64][64];
  const int b = blockIdx.x, t = threadIdx.x;

  if (b < 320) {  // ---- EW[l] = edge_attr @ We[l], 64-row tiles, K=16 ----
    int l = b / 80, et = b % 80;
    const float* A = edge_attr + (size_t)et * 64 * 16;
    const float* W = We + l * 1024;
    float* C = EW + ((size_t)l * EEDGE + et * 64) * 64;
    {
      int r = t >> 2, c0 = (t & 3) * 4;
      float4 v = *(const float4*)(A + r * 16 + c0);
      aT[c0 + 0][r] = v.x; aT[c0 + 1][r] = v.y;
      aT[c0 + 2][r] = v.z; aT[c0 + 3][r] = v.w;
      float4 w = ((const float4*)W)[t];
      *(float4*)&wS[t >> 4][(t & 15) * 4] = w;
    }
    __syncthreads();
    const int rb = (t >> 4) * 4, cb = (t & 15) * 4;
    float acc[4][4] = {};
#pragma unroll
    for (int k = 0; k < 16; ++k) {
      float4 a = *(const float4*)&aT[k][rb];
      float4 w = *(const float4*)&wS[k][cb];
      acc[0][0] += a.x * w.x; acc[0][1] += a.x * w.y; acc[0][2] += a.x * w.z; acc[0][3] += a.x * w.w;
      acc[1][0] += a.y * w.x; acc[1][1] += a.y * w.y; acc[1][2] += a.y * w.z; acc[1][3] += a.y * w.w;
      acc[2][0] += a.z * w.x; acc[2][1] += a.z * w.y; acc[2][2] += a.z * w.z; acc[2][3] += a.z * w.w;
      acc[3][0] += a.w * w.x; acc[3][1] += a.w * w.y; acc[3][2] += a.w * w.z; acc[3][3] += a.w * w.w;
    }
#pragma unroll
    for (int i = 0; i < 4; ++i)
      *(float4*)(C + (size_t)(rb + i) * 64 + cb) =
          make_float4(acc[i][0], acc[i][1], acc[i][2], acc[i][3]);
  } else if (b < 1920) {  // ---- Kh/Vh via MFMA: 64-row tiles -> bf16 ----
    int tid = b - 320;            // 0..1599
    int gy = tid / 200;           // which*4 + l
    int rt = tid % 200;           // 64-row tile index
    int which = gy >> 2, l = gy & 3;
    const float* A = (which ? Vin : Kin) + (size_t)rt * 64 * 64;
    const float* W = (which ? Wv : Wk) + l * 4096;
    unsigned short* C =
        (which ? Vhb : Khb) + ((size_t)l * MKV + (size_t)rt * 64) * 64;
    // stage W (f32, 16 KB)
    for (int i = t; i < 1024; i += 256)
      *(float4*)&wS[i >> 4][(i & 15) * 4] = ((const float4*)W)[i];
    __syncthreads();

    const int w = t >> 6, lane = t & 63;
    const int arow = w * 16 + (lane & 15);   // row within 64-row tile
    const int k0 = (lane >> 4) * 8;
    // A fragments (2 K-halves), f32 -> bf16
    bf16x8 afr[2];
#pragma unroll
    for (int h = 0; h < 2; ++h) {
      const float* ap = A + (size_t)arow * 64 + h * 32 + k0;
      float4 x0 = *(const float4*)ap;
      float4 x1 = *(const float4*)(ap + 4);
      bf16x8 v;
      v[0] = (short)f2bf(x0.x); v[1] = (short)f2bf(x0.y);
      v[2] = (short)f2bf(x0.z); v[3] = (short)f2bf(x0.w);
      v[4] = (short)f2bf(x1.x); v[5] = (short)f2bf(x1.y);
      v[6] = (short)f2bf(x1.z); v[7] = (short)f2bf(x1.w);
      afr[h] = v;
    }
    const int colb = lane & 15;
    const int rowb = w * 16 + (lane >> 4) * 4;
#pragma unroll
    for (int c = 0; c < 4; ++c) {
      const int col = c * 16 + colb;
      f32x4 acc = {0.f, 0.f, 0.f, 0.f};
#pragma unroll
      for (int h = 0; h < 2; ++h) {
        bf16x8 bfr;
#pragma unroll
        for (int j = 0; j < 8; ++j)
          bfr[j] = (short)f2bf(wS[h * 32 + k0 + j][col]);
        acc = __builtin_amdgcn_mfma_f32_16x16x32_bf16(afr[h], bfr, acc, 0, 0, 0);
      }
#pragma unroll
      for (int r = 0; r < 4; ++r)
        C[(size_t)(rowb + r) * 64 + col] = f2bf(acc[r]);
    }
  } else if (b < 2000) {  // ---- zero agg (all layers) ----
    int i = (b - 1920) * 256 + t;
    float4 z = make_float4(0.f, 0.f, 0.f, 0.f);
    for (int j = i; j < NLAYERS * NATOMS * 16; j += 80 * 256)
      ((float4*)agg)[j] = z;
  } else {  // ---- Wmq[l] = Wm[l] @ Wq[l], one block per layer ----
    int l = b - 2000;
    const float* A = Wm + l * 4096;
    const float* B = Wq + l * 4096;
    for (int i = t; i < 1024; i += 256) {
      float4 v = ((const float4*)A)[i];
      *(float4*)&aT[i >> 4][(i & 15) * 4] = v;   // aT holds Wm row-major
    }
    for (int i = t; i < 1024; i += 256) {
      float4 v = ((const float4*)B)[i];
      *(float4*)&wS[i >> 4][(i & 15) * 4] = v;
    }
    __syncthreads();
    int r = t >> 2, c0 = (t & 3) * 16;
    float acc[16] = {};
    for (int j = 0; j < 64; ++j) {
      float a = aT[r][j];
#pragma unroll
      for (int c = 0; c < 16; ++c) acc[c] += a * wS[j][c0 + c];
    }
#pragma unroll
    for (int c = 0; c < 16; c += 4)
      *(float4*)(Wmq + (size_t)l * 4096 + r * 64 + c0 + c) =
          make_float4(acc[c], acc[c + 1], acc[c + 2], acc[c + 3]);
  }
}

// -- per layer: edge messages + scatter-add, AND init xout = xin (residual) ---
__global__ void edge_copy_kernel(const float* __restrict__ xin,
                                 const float* __restrict__ EWl,
                                 const int* __restrict__ src,
                                 const int* __restrict__ dst,
                                 float* __restrict__ agg,
                                 float* __restrict__ xout) {
  int idx = blockIdx.x * 256 + threadIdx.x;  // covers E*64 = 327680
  if (idx < NATOMS * 64) xout[idx] = xin[idx];
  int e = idx >> 6, f = idx & 63;
  float m = xin[src[e] * 64 + f] + EWl[idx];
  m = m / (1.f + __expf(-m));  // silu
  atomicAdd(&agg[dst[e] * 64 + f], m);
}

// -- fused attention (r18 version, unchanged) ---------------------------------
__global__ __launch_bounds__(512) void fused_attn_kernel(
    const float* __restrict__ xin, const float* __restrict__ agg,
    const float* __restrict__ Wq, const float* __restrict__ Wmq,
    const float* __restrict__ Wo, const unsigned short* __restrict__ Khb,
    const unsigned short* __restrict__ Vhb, float* __restrict__ xout) {
  __shared__ union {
    unsigned int Ks2[MPG][9];
    struct {
      float part[16][QH][16];
      float psum[16][QH];
    } r;
  } ku;
  __shared__ unsigned int Vs2[MPG][10];
  __shared__ float P[QH][401];
  __shared__ float Qs[QH][16];

  const int g = blockIdx.x, hd = blockIdx.y, qq = blockIdx.z;
  const int t = threadIdx.x;
  const int hoff = hd * DHEAD;
  const int qbase = g * NPG + qq * QH;
  const int kbase = g * MPG;
  const unsigned int* Kh2 = (const unsigned int*)Khb;
  const unsigned int* Vh2 = (const unsigned int*)Vhb;
  const int hw = hoff >> 1;

  // phase 0: stage K,V (bf16 pairs) + Q head-slice = 0.25*(x@Wq + agg@Wmq)
  for (int i = t; i < MPG * 8; i += 512) {
    int k = i >> 3, j = i & 7;
    ku.Ks2[k][j] = Kh2[(size_t)(kbase + k) * 32 + hw + j];
    Vs2[k][j] = Vh2[(size_t)(kbase + k) * 32 + hw + j];
  }
  if (t < QH * 16) {
    int q = t >> 4, d = t & 15;
    const float* xrow = xin + (qbase + q) * 64;
    const float* arow = agg + (qbase + q) * 64;
    float acc = 0.f;
#pragma unroll 16
    for (int k = 0; k < 64; ++k)
      acc += xrow[k] * Wq[k * 64 + hoff + d] + arow[k] * Wmq[k * 64 + hoff + d];
    Qs[q][d] = acc * 0.25f;
  }
  __syncthreads();

  // phase 1: scores + fused exp (no max; |s| small, f32-safe).
  if (t < 400) {
    const int qg = (t < 200) ? 0 : 5;
    const int kg = (t < 200) ? t : t - 200;
    float acc[5][2] = {};
#pragma unroll
    for (int j = 0; j < 8; ++j) {
      unsigned int ka = ku.Ks2[kg][j], kb = ku.Ks2[kg + 200][j];
      float ka0 = bflo(ka), ka1 = bfhi(ka);
      float kb0 = bflo(kb), kb1 = bfhi(kb);
#pragma unroll
      for (int i = 0; i < 5; ++i) {
        float q0 = Qs[qg + i][2 * j], q1 = Qs[qg + i][2 * j + 1];
        acc[i][0] += q0 * ka0 + q1 * ka1;
        acc[i][1] += q0 * kb0 + q1 * kb1;
      }
    }
#pragma unroll
    for (int i = 0; i < 5; ++i) {
      P[qg + i][kg] = __expf(acc[i][0]);
      P[qg + i][kg + 200] = __expf(acc[i][1]);
    }
  }
  __syncthreads();

  // phase 2: PV register-tiled, 16-way k-split (320 threads): 2q x 4d x 25k.
  if (t < 320) {
    const int dg = (t & 3) * 4;
    const int qp = ((t >> 2) % 5) * 2;
    const int ks = t / 20;
    const int k0 = ks * 25;
    float a0[4] = {}, a1[4] = {};
    float s0 = 0.f, s1 = 0.f;
    for (int k = k0; k < k0 + 25; ++k) {
      float p0 = P[qp][k], p1 = P[qp + 1][k];
      uint2 vv = *(const uint2*)&Vs2[k][dg >> 1];
      float v0 = bflo(vv.x), v1 = bfhi(vv.x);
      float v2 = bflo(vv.y), v3 = bfhi(vv.y);
      a0[0] += p0 * v0; a0[1] += p0 * v1; a0[2] += p0 * v2; a0[3] += p0 * v3;
      a1[0] += p1 * v0; a1[1] += p1 * v1; a1[2] += p1 * v2; a1[3] += p1 * v3;
      s0 += p0; s1 += p1;
    }
    *(float4*)&ku.r.part[ks][qp][dg] = make_float4(a0[0], a0[1], a0[2], a0[3]);
    *(float4*)&ku.r.part[ks][qp + 1][dg] = make_float4(a1[0], a1[1], a1[2], a1[3]);
    if (dg == 0) {
      ku.r.psum[ks][qp] = s0;
      ku.r.psum[ks][qp + 1] = s1;
    }
  }
  __syncthreads();

  // phase 3: reduce partials + sums, normalize -> reuse Qs as o_head
  if (t < QH * 16) {
    int q = t >> 4, d = t & 15;
    float o = 0.f, s = 0.f;
#pragma unroll
    for (int ks = 0; ks < 16; ++ks) {
      o += ku.r.part[ks][q][d];
      s += ku.r.psum[ks][q];
    }
    Qs[q][d] = o / s;
  }
  __syncthreads();

  // phase 4: out-projection partial for this head -> atomicAdd into xout
  for (int i = t; i < QH * 64; i += 512) {
    int q = i >> 6, f = i & 63;
    float acc = 0.f;
#pragma unroll
    for (int d = 0; d < DHEAD; ++d) acc += Qs[q][d] * Wo[(hoff + d) * 64 + f];
    atomicAdd(&xout[(qbase + q) * 64 + f], acc);
  }
}

extern "C" void kernel_launch(void* const* d_in, const int* in_sizes, int n_in,
                              void* d_out, int out_size, void* d_ws, size_t ws_size,
                              hipStream_t stream) {
  const float* x        = (const float*)d_in[0];
  const float* edge_attr= (const float*)d_in[1];
  const float* K        = (const float*)d_in[2];
  const float* V        = (const float*)d_in[3];
  const float* We       = (const float*)d_in[4];
  const float* Wm       = (const float*)d_in[5];
  const float* Wq       = (const float*)d_in[6];
  const float* Wk       = (const float*)d_in[7];
  const float* Wv       = (const float*)d_in[8];
  const float* Wo       = (const float*)d_in[9];
  const int*   eidx     = (const int*)d_in[10];
  const int*   src      = eidx;
  const int*   dst      = eidx + EEDGE;

  unsigned short* Khb = (unsigned short*)d_ws;          // 4*12800*64 bf16
  unsigned short* Vhb = Khb + (size_t)NLAYERS * MKV * 64;
  float* EW   = (float*)(Vhb + (size_t)NLAYERS * MKV * 64);  // 4*5120*64 f32
  float* agg  = EW + (size_t)NLAYERS * EEDGE * 64;           // 4*1280*64
  float* xA   = agg + (size_t)NLAYERS * NATOMS * 64;
  float* xB   = xA + NATOMS * 64;
  float* Wmq  = xB + NATOMS * 64;                            // 4*64*64

  // one precompute kernel: EW + MFMA bf16 Kh/Vh + agg zeroing + Wmq
  precompute_kernel<<<2004, 256, 0, stream>>>(edge_attr, K, V, We, Wk, Wv,
                                              Wm, Wq, EW, Khb, Vhb, agg, Wmq);

  const float* xin = x;
  for (int l = 0; l < NLAYERS; ++l) {
    float* aggl = agg + (size_t)l * NATOMS * 64;
    float* xout = (l == NLAYERS - 1) ? (float*)d_out : ((l & 1) ? xB : xA);
    edge_copy_kernel<<<EEDGE * 64 / 256, 256, 0, stream>>>(
        xin, EW + (size_t)l * EEDGE * 64, src, dst, aggl, xout);
    fused_attn_kernel<<<dim3(NGRAPH, NHEAD, 4), 512, 0, stream>>>(
        xin, aggl, Wq + l * 4096, Wmq + (size_t)l * 4096, Wo + l * 4096,
        Khb + (size_t)l * MKV * 64, Vhb + (size_t)l * MKV * 64, xout);
    xin = xout;
  }
}

// Round 26
// 80.239 us; speedup vs baseline: 1.4919x; 1.0038x over previous
//
#include <hip/hip_runtime.h>
#include <hip/hip_bf16.h>
#include <math.h>

#define NATOMS 1280
#define NHEAD 4
#define DHEAD 16
#define EEDGE 5120
#define MKV 12800
#define NLAYERS 4
#define NGRAPH 32
#define NPG 40      // atoms per graph
#define MPG 400     // kv per graph
#define QH 10       // q rows per attention block (quarter graph)

typedef __attribute__((ext_vector_type(8))) short bf16x8;
typedef __attribute__((ext_vector_type(4))) float f32x4;

__device__ __forceinline__ unsigned short f2bf(float x) {
  __hip_bfloat16 h = __float2bfloat16(x);
  return *reinterpret_cast<unsigned short*>(&h);
}
__device__ __forceinline__ float bflo(unsigned int u) {
  union { unsigned int i; float f; } c; c.i = u << 16; return c.f;
}
__device__ __forceinline__ float bfhi(unsigned int u) {
  union { unsigned int i; float f; } c; c.i = u & 0xffff0000u; return c.f;
}

// ---- precompute: EW GEMM + KV MFMA-GEMM (bf16) + agg zero + Wmq = Wm@Wq -----
// blocks [0,320): EW; [320,1920): KV via MFMA; [1920,2000): zero agg;
// [2000,2004): Wmq
__global__ __launch_bounds__(256) void precompute_kernel(
    const float* __restrict__ edge_attr, const float* __restrict__ Kin,
    const float* __restrict__ Vin, const float* __restrict__ We,
    const float* __restrict__ Wk, const float* __restrict__ Wv,
    const float* __restrict__ Wm, const float* __restrict__ Wq,
    float* __restrict__ EW, unsigned short* __restrict__ Khb,
    unsigned short* __restrict__ Vhb, float* __restrict__ agg,
    float* __restrict__ Wmq) {
  __shared__ float aT[64][132];  // A tile transposed (EW/Wmq branches)
  __shared__ float wS[64][64];
  const int b = blockIdx.x, t = threadIdx.x;

  if (b < 320) {  // ---- EW[l] = edge_attr @ We[l], 64-row tiles, K=16 ----
    int l = b / 80, et = b % 80;
    const float* A = edge_attr + (size_t)et * 64 * 16;
    const float* W = We + l * 1024;
    float* C = EW + ((size_t)l * EEDGE + et * 64) * 64;
    {
      int r = t >> 2, c0 = (t & 3) * 4;
      float4 v = *(const float4*)(A + r * 16 + c0);
      aT[c0 + 0][r] = v.x; aT[c0 + 1][r] = v.y;
      aT[c0 + 2][r] = v.z; aT[c0 + 3][r] = v.w;
      float4 w = ((const float4*)W)[t];
      *(float4*)&wS[t >> 4][(t & 15) * 4] = w;
    }
    __syncthreads();
    const int rb = (t >> 4) * 4, cb = (t & 15) * 4;
    float acc[4][4] = {};
#pragma unroll
    for (int k = 0; k < 16; ++k) {
      float4 a = *(const float4*)&aT[k][rb];
      float4 w = *(const float4*)&wS[k][cb];
      acc[0][0] += a.x * w.x; acc[0][1] += a.x * w.y; acc[0][2] += a.x * w.z; acc[0][3] += a.x * w.w;
      acc[1][0] += a.y * w.x; acc[1][1] += a.y * w.y; acc[1][2] += a.y * w.z; acc[1][3] += a.y * w.w;
      acc[2][0] += a.z * w.x; acc[2][1] += a.z * w.y; acc[2][2] += a.z * w.z; acc[2][3] += a.z * w.w;
      acc[3][0] += a.w * w.x; acc[3][1] += a.w * w.y; acc[3][2] += a.w * w.z; acc[3][3] += a.w * w.w;
    }
#pragma unroll
    for (int i = 0; i < 4; ++i)
      *(float4*)(C + (size_t)(rb + i) * 64 + cb) =
          make_float4(acc[i][0], acc[i][1], acc[i][2], acc[i][3]);
  } else if (b < 1920) {  // ---- Kh/Vh via MFMA: 64-row tiles -> bf16 ----
    int tid = b - 320;            // 0..1599
    int gy = tid / 200;           // which*4 + l
    int rt = tid % 200;           // 64-row tile index
    int which = gy >> 2, l = gy & 3;
    const float* A = (which ? Vin : Kin) + (size_t)rt * 64 * 64;
    const float* W = (which ? Wv : Wk) + l * 4096;
    unsigned short* C =
        (which ? Vhb : Khb) + ((size_t)l * MKV + (size_t)rt * 64) * 64;
    // stage W (f32, 16 KB)
    for (int i = t; i < 1024; i += 256)
      *(float4*)&wS[i >> 4][(i & 15) * 4] = ((const float4*)W)[i];
    __syncthreads();

    const int w = t >> 6, lane = t & 63;
    const int arow = w * 16 + (lane & 15);   // row within 64-row tile
    const int k0 = (lane >> 4) * 8;
    // A fragments (2 K-halves), f32 -> bf16
    bf16x8 afr[2];
#pragma unroll
    for (int h = 0; h < 2; ++h) {
      const float* ap = A + (size_t)arow * 64 + h * 32 + k0;
      float4 x0 = *(const float4*)ap;
      float4 x1 = *(const float4*)(ap + 4);
      bf16x8 v;
      v[0] = (short)f2bf(x0.x); v[1] = (short)f2bf(x0.y);
      v[2] = (short)f2bf(x0.z); v[3] = (short)f2bf(x0.w);
      v[4] = (short)f2bf(x1.x); v[5] = (short)f2bf(x1.y);
      v[6] = (short)f2bf(x1.z); v[7] = (short)f2bf(x1.w);
      afr[h] = v;
    }
    const int colb = lane & 15;
    const int rowb = w * 16 + (lane >> 4) * 4;
#pragma unroll
    for (int c = 0; c < 4; ++c) {
      const int col = c * 16 + colb;
      f32x4 acc = {0.f, 0.f, 0.f, 0.f};
#pragma unroll
      for (int h = 0; h < 2; ++h) {
        bf16x8 bfr;
#pragma unroll
        for (int j = 0; j < 8; ++j)
          bfr[j] = (short)f2bf(wS[h * 32 + k0 + j][col]);
        acc = __builtin_amdgcn_mfma_f32_16x16x32_bf16(afr[h], bfr, acc, 0, 0, 0);
      }
#pragma unroll
      for (int r = 0; r < 4; ++r)
        C[(size_t)(rowb + r) * 64 + col] = f2bf(acc[r]);
    }
  } else if (b < 2000) {  // ---- zero agg (all layers) ----
    int i = (b - 1920) * 256 + t;
    float4 z = make_float4(0.f, 0.f, 0.f, 0.f);
    for (int j = i; j < NLAYERS * NATOMS * 16; j += 80 * 256)
      ((float4*)agg)[j] = z;
  } else {  // ---- Wmq[l] = Wm[l] @ Wq[l], one block per layer ----
    int l = b - 2000;
    const float* A = Wm + l * 4096;
    const float* B = Wq + l * 4096;
    for (int i = t; i < 1024; i += 256) {
      float4 v = ((const float4*)A)[i];
      *(float4*)&aT[i >> 4][(i & 15) * 4] = v;   // aT holds Wm row-major
    }
    for (int i = t; i < 1024; i += 256) {
      float4 v = ((const float4*)B)[i];
      *(float4*)&wS[i >> 4][(i & 15) * 4] = v;
    }
    __syncthreads();
    int r = t >> 2, c0 = (t & 3) * 16;
    float acc[16] = {};
    for (int j = 0; j < 64; ++j) {
      float a = aT[r][j];
#pragma unroll
      for (int c = 0; c < 16; ++c) acc[c] += a * wS[j][c0 + c];
    }
#pragma unroll
    for (int c = 0; c < 16; c += 4)
      *(float4*)(Wmq + (size_t)l * 4096 + r * 64 + c0 + c) =
          make_float4(acc[c], acc[c + 1], acc[c + 2], acc[c + 3]);
  }
}

// -- per layer: edge messages + scatter-add, AND init xout = xin (residual) ---
__global__ void edge_copy_kernel(const float* __restrict__ xin,
                                 const float* __restrict__ EWl,
                                 const int* __restrict__ src,
                                 const int* __restrict__ dst,
                                 float* __restrict__ agg,
                                 float* __restrict__ xout) {
  int idx = blockIdx.x * 256 + threadIdx.x;  // covers E*64 = 327680
  if (idx < NATOMS * 64) xout[idx] = xin[idx];
  int e = idx >> 6, f = idx & 63;
  float m = xin[src[e] * 64 + f] + EWl[idx];
  m = m / (1.f + __expf(-m));  // silu
  atomicAdd(&agg[dst[e] * 64 + f], m);
}

// -- fused attention (r18 version, unchanged) ---------------------------------
__global__ __launch_bounds__(512) void fused_attn_kernel(
    const float* __restrict__ xin, const float* __restrict__ agg,
    const float* __restrict__ Wq, const float* __restrict__ Wmq,
    const float* __restrict__ Wo, const unsigned short* __restrict__ Khb,
    const unsigned short* __restrict__ Vhb, float* __restrict__ xout) {
  __shared__ union {
    unsigned int Ks2[MPG][9];
    struct {
      float part[16][QH][16];
      float psum[16][QH];
    } r;
  } ku;
  __shared__ unsigned int Vs2[MPG][10];
  __shared__ float P[QH][401];
  __shared__ float Qs[QH][16];

  const int g = blockIdx.x, hd = blockIdx.y, qq = blockIdx.z;
  const int t = threadIdx.x;
  const int hoff = hd * DHEAD;
  const int qbase = g * NPG + qq * QH;
  const int kbase = g * MPG;
  const unsigned int* Kh2 = (const unsigned int*)Khb;
  const unsigned int* Vh2 = (const unsigned int*)Vhb;
  const int hw = hoff >> 1;

  // phase 0: stage K,V (bf16 pairs) + Q head-slice = 0.25*(x@Wq + agg@Wmq)
  for (int i = t; i < MPG * 8; i += 512) {
    int k = i >> 3, j = i & 7;
    ku.Ks2[k][j] = Kh2[(size_t)(kbase + k) * 32 + hw + j];
    Vs2[k][j] = Vh2[(size_t)(kbase + k) * 32 + hw + j];
  }
  if (t < QH * 16) {
    int q = t >> 4, d = t & 15;
    const float* xrow = xin + (qbase + q) * 64;
    const float* arow = agg + (qbase + q) * 64;
    float acc = 0.f;
#pragma unroll 16
    for (int k = 0; k < 64; ++k)
      acc += xrow[k] * Wq[k * 64 + hoff + d] + arow[k] * Wmq[k * 64 + hoff + d];
    Qs[q][d] = acc * 0.25f;
  }
  __syncthreads();

  // phase 1: scores + fused exp (no max; |s| small, f32-safe).
  if (t < 400) {
    const int qg = (t < 200) ? 0 : 5;
    const int kg = (t < 200) ? t : t - 200;
    float acc[5][2] = {};
#pragma unroll
    for (int j = 0; j < 8; ++j) {
      unsigned int ka = ku.Ks2[kg][j], kb = ku.Ks2[kg + 200][j];
      float ka0 = bflo(ka), ka1 = bfhi(ka);
      float kb0 = bflo(kb), kb1 = bfhi(kb);
#pragma unroll
      for (int i = 0; i < 5; ++i) {
        float q0 = Qs[qg + i][2 * j], q1 = Qs[qg + i][2 * j + 1];
        acc[i][0] += q0 * ka0 + q1 * ka1;
        acc[i][1] += q0 * kb0 + q1 * kb1;
      }
    }
#pragma unroll
    for (int i = 0; i < 5; ++i) {
      P[qg + i][kg] = __expf(acc[i][0]);
      P[qg + i][kg + 200] = __expf(acc[i][1]);
    }
  }
  __syncthreads();

  // phase 2: PV register-tiled, 16-way k-split (320 threads): 2q x 4d x 25k.
  if (t < 320) {
    const int dg = (t & 3) * 4;
    const int qp = ((t >> 2) % 5) * 2;
    const int ks = t / 20;
    const int k0 = ks * 25;
    float a0[4] = {}, a1[4] = {};
    float s0 = 0.f, s1 = 0.f;
    for (int k = k0; k < k0 + 25; ++k) {
      float p0 = P[qp][k], p1 = P[qp + 1][k];
      uint2 vv = *(const uint2*)&Vs2[k][dg >> 1];
      float v0 = bflo(vv.x), v1 = bfhi(vv.x);
      float v2 = bflo(vv.y), v3 = bfhi(vv.y);
      a0[0] += p0 * v0; a0[1] += p0 * v1; a0[2] += p0 * v2; a0[3] += p0 * v3;
      a1[0] += p1 * v0; a1[1] += p1 * v1; a1[2] += p1 * v2; a1[3] += p1 * v3;
      s0 += p0; s1 += p1;
    }
    *(float4*)&ku.r.part[ks][qp][dg] = make_float4(a0[0], a0[1], a0[2], a0[3]);
    *(float4*)&ku.r.part[ks][qp + 1][dg] = make_float4(a1[0], a1[1], a1[2], a1[3]);
    if (dg == 0) {
      ku.r.psum[ks][qp] = s0;
      ku.r.psum[ks][qp + 1] = s1;
    }
  }
  __syncthreads();

  // phase 3: reduce partials + sums, normalize -> reuse Qs as o_head
  if (t < QH * 16) {
    int q = t >> 4, d = t & 15;
    float o = 0.f, s = 0.f;
#pragma unroll
    for (int ks = 0; ks < 16; ++ks) {
      o += ku.r.part[ks][q][d];
      s += ku.r.psum[ks][q];
    }
    Qs[q][d] = o / s;
  }
  __syncthreads();

  // phase 4: out-projection partial for this head -> atomicAdd into xout
  for (int i = t; i < QH * 64; i += 512) {
    int q = i >> 6, f = i & 63;
    float acc = 0.f;
#pragma unroll
    for (int d = 0; d < DHEAD; ++d) acc += Qs[q][d] * Wo[(hoff + d) * 64 + f];
    atomicAdd(&xout[(qbase + q) * 64 + f], acc);
  }
}

extern "C" void kernel_launch(void* const* d_in, const int* in_sizes, int n_in,
                              void* d_out, int out_size, void* d_ws, size_t ws_size,
                              hipStream_t stream) {
  const float* x        = (const float*)d_in[0];
  const float* edge_attr= (const float*)d_in[1];
  const float* K        = (const float*)d_in[2];
  const float* V        = (const float*)d_in[3];
  const float* We       = (const float*)d_in[4];
  const float* Wm       = (const float*)d_in[5];
  const float* Wq       = (const float*)d_in[6];
  const float* Wk       = (const float*)d_in[7];
  const float* Wv       = (const float*)d_in[8];
  const float* Wo       = (const float*)d_in[9];
  const int*   eidx     = (const int*)d_in[10];
  const int*   src      = eidx;
  const int*   dst      = eidx + EEDGE;

  unsigned short* Khb = (unsigned short*)d_ws;          // 4*12800*64 bf16
  unsigned short* Vhb = Khb + (size_t)NLAYERS * MKV * 64;
  float* EW   = (float*)(Vhb + (size_t)NLAYERS * MKV * 64);  // 4*5120*64 f32
  float* agg  = EW + (size_t)NLAYERS * EEDGE * 64;           // 4*1280*64
  float* xA   = agg + (size_t)NLAYERS * NATOMS * 64;
  float* xB   = xA + NATOMS * 64;
  float* Wmq  = xB + NATOMS * 64;                            // 4*64*64

  // one precompute kernel: EW + MFMA bf16 Kh/Vh + agg zeroing + Wmq
  precompute_kernel<<<2004, 256, 0, stream>>>(edge_attr, K, V, We, Wk, Wv,
                                              Wm, Wq, EW, Khb, Vhb, agg, Wmq);

  const float* xin = x;
  for (int l = 0; l < NLAYERS; ++l) {
    float* aggl = agg + (size_t)l * NATOMS * 64;
    float* xout = (l == NLAYERS - 1) ? (float*)d_out : ((l & 1) ? xB : xA);
    edge_copy_kernel<<<EEDGE * 64 / 256, 256, 0, stream>>>(
        xin, EW + (size_t)l * EEDGE * 64, src, dst, aggl, xout);
    fused_attn_kernel<<<dim3(NGRAPH, NHEAD, 4), 512, 0, stream>>>(
        xin, aggl, Wq + l * 4096, Wmq + (size_t)l * 4096, Wo + l * 4096,
        Khb + (size_t)l * MKV * 64, Vhb + (size_t)l * MKV * 64, xout);
    xin = xout;
  }
}